// Round 3
// baseline (98.190 us; speedup 1.0000x reference)
//
#include <hip/hip_runtime.h>
#include <hip/hip_bf16.h>

#define N_TOK  1728     // 12*12*12
#define CDIM   64
#define NHEADS 32       // head_dim = 2
#define NQT    27       // query tiles of 64
#define NPAIR  (N_TOK / 2)             // 864 fp16 key-pairs per head
#define SEGS   4                       // key segments per block (1 per wave)
#define SEGLEN (NPAIR / SEGS)          // 216 uint4 = 432 keys per wave
#define SCALE  0.70710678118654752f    // 1/sqrt(2)
#define LOG2E  1.44269504088896340736f
#define NBIAS  (-10.0f)                // softmax shift so exp2 fits fp16
                                       //  (max score ~20 -> ea <= 2^10 << 65504;
                                       //   ratio p/l is shift-invariant)

typedef _Float16 h2 __attribute__((ext_vector_type(2)));
typedef __fp16   hf2 __attribute__((ext_vector_type(2)));   // builtin ret type
union H2U { h2 h; hf2 hf; unsigned int u; };

__device__ __forceinline__ unsigned int pack2(float a, float b) {
    H2U c; c.h.x = (_Float16)a; c.h.y = (_Float16)b; return c.u;
}
// fp16 dot2 with fp32 accumulator: v_dot2_f32_f16
__device__ __forceinline__ float hdot2a(unsigned int q, unsigned int k, float c) {
    H2U a, b; a.u = q; b.u = k;
#if __has_builtin(__builtin_amdgcn_fdot2)
    return __builtin_amdgcn_fdot2(a.h, b.h, c, false);
#else
    return fmaf((float)a.h.x, (float)b.h.x, fmaf((float)a.h.y, (float)b.h.y, c));
#endif
}
__device__ __forceinline__ float fd2(h2 a, h2 b, float c) {
#if __has_builtin(__builtin_amdgcn_fdot2)
    return __builtin_amdgcn_fdot2(a, b, c, false);
#else
    return fmaf((float)a.x, (float)b.x, fmaf((float)a.y, (float)b.y, c));
#endif
}
// single-instruction (f32,f32)->f16x2 pack: v_cvt_pkrtz_f16_f32
__device__ __forceinline__ unsigned int pk2u(float a, float b) {
#if __has_builtin(__builtin_amdgcn_cvt_pkrtz)
    H2U c; c.hf = __builtin_amdgcn_cvt_pkrtz(a, b); return c.u;
#else
    return pack2(a, b);
#endif
}

// ---- dtype-adaptive load: f32=1 -> fp32 buffer, 0 -> bf16 buffer ----
__device__ __forceinline__ float ldin(const void* p, int i, int f32) {
    if (f32) return ((const float*)p)[i];
    union { unsigned int b; float f; } c;
    c.b = ((unsigned int)((const unsigned short*)p)[i]) << 16;
    return c.f;
}
// ---- wave-local dtype sniff (R1-proven: inputs are fp32 at runtime) ----
__device__ __forceinline__ int sniff_f32(const void* x) {
    union { unsigned int b; float f; } c;
    c.b = ((unsigned int)((const unsigned short*)x)[threadIdx.x & 63]) << 16;
    int bad = (((c.b >> 23) & 0xFF) == 0xFF) || (fabsf(c.f) > 1e10f);
    return (__ballot(bad) != 0ULL) ? 1 : 0;
}

// ========== Kernel 1: QKV -> packed fp16 Q / KV in ws ==========
// grid (27, 96), block 64. y -> (h = y&31, which = y>>5 in {q,k,v}).
// x reads coalesced over lanes, weight rows wave-uniform -> scalar pipe.
// V is packed TRANSPOSED within each key-pair so the attn kernel
// can consume it with v_dot2_f32_f16:
//   uint4 = { (kx,ky)_e, (kx,ky)_o, (vx_e,vx_o), (vy_e,vy_o) }
__global__ void __launch_bounds__(64)
qkv_pack(const void* __restrict__ xv, const void* __restrict__ wv,
         unsigned int* __restrict__ Qp, unsigned int* __restrict__ KVg) {
    const int f     = sniff_f32(xv);
    const int lane  = threadIdx.x;
    const int h     = blockIdx.y & 31;
    const int which = blockIdx.y >> 5;
    const int r0    = (which << 6) + 2 * h;        // uniform -> s_loads
    const int n     = blockIdx.x * 64 + lane;
    float a0 = 0.f, a1 = 0.f;
    if (f) {
        const float* x  = (const float*)xv;
        const float* w0 = (const float*)wv + r0 * CDIM;
        const float* w1 = w0 + CDIM;
#pragma unroll 8
        for (int c = 0; c < CDIM; ++c) {
            float xc = x[c * N_TOK + n];           // coalesced
            a0 = fmaf(xc, w0[c], a0);
            a1 = fmaf(xc, w1[c], a1);
        }
    } else {
#pragma unroll 8
        for (int c = 0; c < CDIM; ++c) {
            float xc = ldin(xv, c * N_TOK + n, 0);
            a0 = fmaf(xc, ldin(wv, r0 * CDIM + c, 0), a0);
            a1 = fmaf(xc, ldin(wv, (r0 + 1) * CDIM + c, 0), a1);
        }
    }
    if (which == 0) {
        Qp[h * N_TOK + n] = pack2(a0 * (SCALE * LOG2E), a1 * (SCALE * LOG2E));
    } else if (which == 1) {
        KVg[(h * NPAIR + (n >> 1)) * 4 + (n & 1)] = pack2(a0, a1);
    } else {
        // V: transpose within the (even,odd) token pair via lane exchange
        float b0 = __shfl_xor(a0, 1);   // partner's vx
        float b1 = __shfl_xor(a1, 1);   // partner's vy
        unsigned int val = (n & 1) ? pack2(b1, a1)    // odd  -> w=(vy_e,vy_o)
                                   : pack2(a0, b0);   // even -> z=(vx_e,vx_o)
        KVg[(h * NPAIR + (n >> 1)) * 4 + 2 + (n & 1)] = val;
    }
}

// ========== Kernel 2: attention — SGPR key stream (R17) ==========
// grid (27 query-tiles, 32 heads) = 864 blocks x 256 threads (4 waves).
// lane = query (64/tile), wave = one wave-uniform key segment (216 uint4).
// Keys stream via s_load (scalar cache; 13.8 KB/head fits) and feed
// v_dot2_f32_f16 as the single legal SGPR operand. This removes ALL LDS
// traffic from the hot loop (R2's 108 ds_read_b128/wave ~ 14 us chip-wide
// of shared-LDS issue) plus the staging loop and its __syncthreads.
// Per uint4 (2 keys): 2 dot2 + 2 exp2 + 1 cvt_pkrtz + 3 dot2, zero LDS.
__global__ void __launch_bounds__(256, 4)
attn_kernel(const unsigned int* __restrict__ Qp, const uint4* __restrict__ KVg,
            float* __restrict__ O) {
    __shared__ float redbuf[SEGS * 193];   // 4 x (64*3 +1 pad) = 3088 B
    const int tid  = threadIdx.x;
    const int lane = tid & 63;
    const int wav  = __builtin_amdgcn_readfirstlane(tid >> 6);  // uniform
    const int qt   = blockIdx.x;           // query tile [0,27)
    const int h    = blockIdx.y;
    const int t0   = qt * 64;

    const unsigned int qh = Qp[h * N_TOK + t0 + lane];   // coalesced 256B
    const uint4* __restrict__ Kp = KVg + h * NPAIR + wav * SEGLEN; // uniform

    float nb = NBIAS;
    asm("" : "+v"(nb));                    // pin bias in a VGPR so each dot2
                                           // uses its 1-SGPR slot for the key
    H2U one2; one2.u = 0x3C003C00u;        // (1.0h, 1.0h)
    float l0 = 0.f, l1 = 0.f, l2 = 0.f, l3 = 0.f;
    float p0 = 0.f, p1 = 0.f, p2 = 0.f, p3 = 0.f;
    float s0 = 0.f, s1 = 0.f, s2 = 0.f, s3 = 0.f;
    for (int g = 0; g < SEGLEN; g += 4) {
        uint4 d0 = Kp[g], d1 = Kp[g + 1], d2 = Kp[g + 2], d3 = Kp[g + 3];
        float ea, eb; H2U pe, vz, vw;

        ea = __builtin_amdgcn_exp2f(hdot2a(qh, d0.x, nb));
        eb = __builtin_amdgcn_exp2f(hdot2a(qh, d0.y, nb));
        pe.u = pk2u(ea, eb);
        vz.u = d0.z; vw.u = d0.w;
        l0 = fd2(pe.h, one2.h, l0);
        p0 = fd2(pe.h, vz.h, p0);
        s0 = fd2(pe.h, vw.h, s0);

        ea = __builtin_amdgcn_exp2f(hdot2a(qh, d1.x, nb));
        eb = __builtin_amdgcn_exp2f(hdot2a(qh, d1.y, nb));
        pe.u = pk2u(ea, eb);
        vz.u = d1.z; vw.u = d1.w;
        l1 = fd2(pe.h, one2.h, l1);
        p1 = fd2(pe.h, vz.h, p1);
        s1 = fd2(pe.h, vw.h, s1);

        ea = __builtin_amdgcn_exp2f(hdot2a(qh, d2.x, nb));
        eb = __builtin_amdgcn_exp2f(hdot2a(qh, d2.y, nb));
        pe.u = pk2u(ea, eb);
        vz.u = d2.z; vw.u = d2.w;
        l2 = fd2(pe.h, one2.h, l2);
        p2 = fd2(pe.h, vz.h, p2);
        s2 = fd2(pe.h, vw.h, s2);

        ea = __builtin_amdgcn_exp2f(hdot2a(qh, d3.x, nb));
        eb = __builtin_amdgcn_exp2f(hdot2a(qh, d3.y, nb));
        pe.u = pk2u(ea, eb);
        vz.u = d3.z; vw.u = d3.w;
        l3 = fd2(pe.h, one2.h, l3);
        p3 = fd2(pe.h, vz.h, p3);
        s3 = fd2(pe.h, vw.h, s3);
    }
    float L = (l0 + l1) + (l2 + l3);
    float A = (p0 + p1) + (p2 + p3);
    float B = (s0 + s1) + (s2 + s3);
    // cross-wave (key-segment) reduction via tiny LDS buffer
    {
        float* r = redbuf + wav * 193 + lane * 3;   // 3*lane mod 32: 2-way, free
        r[0] = L; r[1] = A; r[2] = B;
    }
    __syncthreads();
    if (wav == 0) {
        float Lt = 0.f, At = 0.f, Bt = 0.f;
#pragma unroll
        for (int w = 0; w < SEGS; ++w) {
            const float* r = redbuf + w * 193 + lane * 3;
            Lt += r[0]; At += r[1]; Bt += r[2];
        }
        float inv = 1.0f / Lt;
        *((float2*)(O + (t0 + lane) * CDIM + 2 * h)) =
            make_float2(At * inv, Bt * inv);
    }
}

// ========== Kernel 3: output projection (R9-proven, unchanged) ==========
__global__ void __launch_bounds__(256)
proj_kernel(const void* __restrict__ xv,   // dtype sniff only
            const float* __restrict__ O,
            const void* __restrict__ w_proj, const void* __restrict__ b_proj,
            void* __restrict__ out) {
    __shared__ float Ws[CDIM * 65];        // 16640 B
    const int f    = sniff_f32(xv);
    const int tid  = threadIdx.x;
    const int lane = tid & 63;
    const int wav  = tid >> 6;
    for (int e = tid; e < CDIM * CDIM; e += 256)    // e = co*64+ci, coalesced
        Ws[(e & 63) * 65 + (e >> 6)] = ldin(w_proj, e, f);
    __syncthreads();
    int n = blockIdx.x * 4 + wav;          // 432*4 = 1728
    float acc = ldin(b_proj, lane, f);
#pragma unroll 8
    for (int ci = 0; ci < CDIM; ++ci)
        acc = fmaf(O[n * CDIM + ci],                 // uniform -> s_load
                   Ws[ci * 65 + lane], acc);          // bank-conflict-free
    if (f) ((float*)out)[n * CDIM + lane] = acc;
    else   ((__hip_bfloat16*)out)[n * CDIM + lane] = __float2bfloat16(acc);
}

extern "C" void kernel_launch(void* const* d_in, const int* in_sizes, int n_in,
                              void* d_out, int out_size, void* d_ws, size_t ws_size,
                              hipStream_t stream) {
    const void* x      = d_in[0];
    const void* w_qkv  = d_in[1];
    const void* w_proj = d_in[2];
    const void* b_proj = d_in[3];

    // ws layout (~1.11 MB of the proven >=1.77 MB):
    float*        O   = (float*)d_ws;                    // 442368 B [1728][64]
    unsigned int* Qp  = (unsigned int*)(O + N_TOK * CDIM);     // 221184 B
    unsigned int* KVg = Qp + NHEADS * N_TOK;                   // 442368 B

    qkv_pack   <<<dim3(27, 96), 64, 0, stream>>>(x, w_qkv, Qp, KVg);
    attn_kernel<<<dim3(NQT, NHEADS), 256, 0, stream>>>(Qp, (const uint4*)KVg, O);
    proj_kernel<<<432, 256, 0, stream>>>(x, O, w_proj, b_proj, d_out);
}

// Round 4
// 89.245 us; speedup vs baseline: 1.1002x; 1.1002x over previous
//
#include <hip/hip_runtime.h>
#include <hip/hip_bf16.h>

#define N_TOK  1728     // 12*12*12
#define CDIM   64
#define NHEADS 32       // head_dim = 2
#define NHT    54       // half-tiles of 32 queries
#define NPAIR  (N_TOK / 2)             // 864 fp16 key-pairs per head
#define SEGS   8                       // key segments per block (2 per wave)
#define SEGLEN (NPAIR / SEGS)          // 108 uint4 = 216 keys
#define SEGSTR (SEGLEN + 1)            // +1 uint4 pad -> disjoint banks for
                                       //  the two per-wave broadcast addrs
#define SCALE  0.70710678118654752f    // 1/sqrt(2)
#define LOG2E  1.44269504088896340736f
#define NBIAS  (-10.0f)                // softmax shift so exp2 fits fp16
                                       //  (max score ~20 -> ea <= 2^10 << 65504;
                                       //   ratio p/l is shift-invariant)

typedef _Float16 h2 __attribute__((ext_vector_type(2)));
typedef __fp16   hf2 __attribute__((ext_vector_type(2)));   // builtin ret type
union H2U { h2 h; hf2 hf; unsigned int u; };

__device__ __forceinline__ unsigned int pack2(float a, float b) {
    H2U c; c.h.x = (_Float16)a; c.h.y = (_Float16)b; return c.u;
}
// fp16 dot2 with fp32 accumulator: v_dot2_f32_f16
__device__ __forceinline__ float hdot2a(unsigned int q, unsigned int k, float c) {
    H2U a, b; a.u = q; b.u = k;
#if __has_builtin(__builtin_amdgcn_fdot2)
    return __builtin_amdgcn_fdot2(a.h, b.h, c, false);
#else
    return fmaf((float)a.h.x, (float)b.h.x, fmaf((float)a.h.y, (float)b.h.y, c));
#endif
}
__device__ __forceinline__ float fd2(h2 a, h2 b, float c) {
#if __has_builtin(__builtin_amdgcn_fdot2)
    return __builtin_amdgcn_fdot2(a, b, c, false);
#else
    return fmaf((float)a.x, (float)b.x, fmaf((float)a.y, (float)b.y, c));
#endif
}
// single-instruction (f32,f32)->f16x2 pack: v_cvt_pkrtz_f16_f32
__device__ __forceinline__ unsigned int pk2u(float a, float b) {
#if __has_builtin(__builtin_amdgcn_cvt_pkrtz)
    H2U c; c.hf = __builtin_amdgcn_cvt_pkrtz(a, b); return c.u;
#else
    return pack2(a, b);
#endif
}

// ---- dtype-adaptive load: f32=1 -> fp32 buffer, 0 -> bf16 buffer ----
__device__ __forceinline__ float ldin(const void* p, int i, int f32) {
    if (f32) return ((const float*)p)[i];
    union { unsigned int b; float f; } c;
    c.b = ((unsigned int)((const unsigned short*)p)[i]) << 16;
    return c.f;
}
// ---- wave-local dtype sniff (R1-proven: inputs are fp32 at runtime) ----
__device__ __forceinline__ int sniff_f32(const void* x) {
    union { unsigned int b; float f; } c;
    c.b = ((unsigned int)((const unsigned short*)x)[threadIdx.x & 63]) << 16;
    int bad = (((c.b >> 23) & 0xFF) == 0xFF) || (fabsf(c.f) > 1e10f);
    return (__ballot(bad) != 0ULL) ? 1 : 0;
}

// ========== Kernel 1: QKV -> packed fp16 Q / KV in ws ==========
// grid (27, 96), block 64. y -> (h = y&31, which = y>>5 in {q,k,v}).
// x reads coalesced over lanes, weight rows wave-uniform -> scalar pipe.
// V is packed TRANSPOSED within each key-pair so the attn kernel
// can consume it with v_dot2_f32_f16:
//   uint4 = { (kx,ky)_e, (kx,ky)_o, (vx_e,vx_o), (vy_e,vy_o) }
__global__ void __launch_bounds__(64)
qkv_pack(const void* __restrict__ xv, const void* __restrict__ wv,
         unsigned int* __restrict__ Qp, unsigned int* __restrict__ KVg) {
    const int f     = sniff_f32(xv);
    const int lane  = threadIdx.x;
    const int h     = blockIdx.y & 31;
    const int which = blockIdx.y >> 5;
    const int r0    = (which << 6) + 2 * h;        // uniform -> s_loads
    const int n     = blockIdx.x * 64 + lane;
    float a0 = 0.f, a1 = 0.f;
    if (f) {
        const float* x  = (const float*)xv;
        const float* w0 = (const float*)wv + r0 * CDIM;
        const float* w1 = w0 + CDIM;
#pragma unroll 8
        for (int c = 0; c < CDIM; ++c) {
            float xc = x[c * N_TOK + n];           // coalesced
            a0 = fmaf(xc, w0[c], a0);
            a1 = fmaf(xc, w1[c], a1);
        }
    } else {
#pragma unroll 8
        for (int c = 0; c < CDIM; ++c) {
            float xc = ldin(xv, c * N_TOK + n, 0);
            a0 = fmaf(xc, ldin(wv, r0 * CDIM + c, 0), a0);
            a1 = fmaf(xc, ldin(wv, (r0 + 1) * CDIM + c, 0), a1);
        }
    }
    if (which == 0) {
        Qp[h * N_TOK + n] = pack2(a0 * (SCALE * LOG2E), a1 * (SCALE * LOG2E));
    } else if (which == 1) {
        KVg[(h * NPAIR + (n >> 1)) * 4 + (n & 1)] = pack2(a0, a1);
    } else {
        // V: transpose within the (even,odd) token pair via lane exchange
        float b0 = __shfl_xor(a0, 1);   // partner's vx
        float b1 = __shfl_xor(a1, 1);   // partner's vy
        unsigned int val = (n & 1) ? pack2(b1, a1)    // odd  -> w=(vy_e,vy_o)
                                   : pack2(a0, b0);   // even -> z=(vx_e,vx_o)
        KVg[(h * NPAIR + (n >> 1)) * 4 + 2 + (n & 1)] = val;
    }
}

// ========== Kernel 2: attention — R2 structure + per-wave staging ==========
// grid (54 half-tiles, 32 heads) = 1728 blocks x 256 threads (4 waves).
// Balance: 6.75 blocks/CU at 8/CU capacity -> makespan 1.04x. Each lane:
// 216 keys; half-wave segments read 2 broadcast addrs/wave from seg-padded
// LDS (disjoint banks). R18: each wave stages exactly the two segments it
// reads -> NO pre-loop __syncthreads (wave-local lgkmcnt ordering only);
// each wave enters its hot loop as soon as its own 4 staging loads land.
// Hot loop per uint4 (2 keys): 2 dot2 + 2 exp2 + 1 cvt_pkrtz + 3 dot2
// (R16-proven); fp16 softmax weights, -10 bias rides the dot2 c-operand.
__global__ void __launch_bounds__(256, 8)
attn_kernel(const unsigned int* __restrict__ Qp, const uint4* __restrict__ KVg,
            float* __restrict__ O) {
    __shared__ uint4 KVs[SEGS * SEGSTR];   // 13952 B
    __shared__ float redbuf[4 * 32 * 3];   //  1536 B
    const int tid  = threadIdx.x;
    const int lane = tid & 63;
    const int wav  = tid >> 6;
    const int ht   = blockIdx.x;           // half-tile [0,54)
    const int h    = blockIdx.y;
    const int t0   = ht * 32;
    const int q    = lane & 31;            // query within half-tile
    const int seg  = (wav << 1) | (lane >> 5);   // [0,8)

    // per-wave staging: wave w loads segments {2w, 2w+1} (216 uint4),
    // coalesced 1KB bursts; scatter into seg-padded LDS it alone reads.
    const int base = (wav << 1) * SEGLEN;
    for (int e = lane; e < 2 * SEGLEN; e += 64) {
        int ge = base + e;
        KVs[(ge / SEGLEN) * SEGSTR + (ge % SEGLEN)] = KVg[h * NPAIR + ge];
    }
    const unsigned int qh = Qp[h * N_TOK + t0 + q];    // 32-dword broadcast
    // no __syncthreads: reads below hit only this wave's writes (lgkmcnt)

    // 108 uint4 (216 keys) per lane; 4 independent chains
    const uint4* KVp = &KVs[seg * SEGSTR];
    const float nb = NBIAS;
    H2U one2; one2.u = 0x3C003C00u;        // (1.0h, 1.0h)
    float l0 = 0.f, l1 = 0.f, l2 = 0.f, l3 = 0.f;
    float p0 = 0.f, p1 = 0.f, p2 = 0.f, p3 = 0.f;
    float s0 = 0.f, s1 = 0.f, s2 = 0.f, s3 = 0.f;
#pragma unroll
    for (int g = 0; g < SEGLEN; g += 4) {
        uint4 d0 = KVp[g], d1 = KVp[g + 1], d2 = KVp[g + 2], d3 = KVp[g + 3];
        float ea, eb; H2U pe, vz, vw;

        ea = __builtin_amdgcn_exp2f(hdot2a(qh, d0.x, nb));
        eb = __builtin_amdgcn_exp2f(hdot2a(qh, d0.y, nb));
        pe.u = pk2u(ea, eb);
        vz.u = d0.z; vw.u = d0.w;
        l0 = fd2(pe.h, one2.h, l0);
        p0 = fd2(pe.h, vz.h, p0);
        s0 = fd2(pe.h, vw.h, s0);

        ea = __builtin_amdgcn_exp2f(hdot2a(qh, d1.x, nb));
        eb = __builtin_amdgcn_exp2f(hdot2a(qh, d1.y, nb));
        pe.u = pk2u(ea, eb);
        vz.u = d1.z; vw.u = d1.w;
        l1 = fd2(pe.h, one2.h, l1);
        p1 = fd2(pe.h, vz.h, p1);
        s1 = fd2(pe.h, vw.h, s1);

        ea = __builtin_amdgcn_exp2f(hdot2a(qh, d2.x, nb));
        eb = __builtin_amdgcn_exp2f(hdot2a(qh, d2.y, nb));
        pe.u = pk2u(ea, eb);
        vz.u = d2.z; vw.u = d2.w;
        l2 = fd2(pe.h, one2.h, l2);
        p2 = fd2(pe.h, vz.h, p2);
        s2 = fd2(pe.h, vw.h, s2);

        ea = __builtin_amdgcn_exp2f(hdot2a(qh, d3.x, nb));
        eb = __builtin_amdgcn_exp2f(hdot2a(qh, d3.y, nb));
        pe.u = pk2u(ea, eb);
        vz.u = d3.z; vw.u = d3.w;
        l3 = fd2(pe.h, one2.h, l3);
        p3 = fd2(pe.h, vz.h, p3);
        s3 = fd2(pe.h, vw.h, s3);
    }
    float L = (l0 + l1) + (l2 + l3);
    float A = (p0 + p1) + (p2 + p3);
    float B = (s0 + s1) + (s2 + s3);
    // combine the two half-wave segments, then cross-wave via LDS
    L += __shfl_xor(L, 32); A += __shfl_xor(A, 32); B += __shfl_xor(B, 32);
    if (lane < 32) {
        float* r = redbuf + wav * 96 + q * 3;   // 3q mod 32: conflict-free
        r[0] = L; r[1] = A; r[2] = B;
    }
    __syncthreads();
    if (wav == 0 && lane < 32) {
        float Lt = 0.f, At = 0.f, Bt = 0.f;
#pragma unroll
        for (int w = 0; w < 4; ++w) {
            const float* r = redbuf + w * 96 + q * 3;
            Lt += r[0]; At += r[1]; Bt += r[2];
        }
        float inv = 1.0f / Lt;
        *((float2*)(O + (t0 + q) * CDIM + 2 * h)) =
            make_float2(At * inv, Bt * inv);
    }
}

// ========== Kernel 3: output projection (R9-proven, unchanged) ==========
__global__ void __launch_bounds__(256)
proj_kernel(const void* __restrict__ xv,   // dtype sniff only
            const float* __restrict__ O,
            const void* __restrict__ w_proj, const void* __restrict__ b_proj,
            void* __restrict__ out) {
    __shared__ float Ws[CDIM * 65];        // 16640 B
    const int f    = sniff_f32(xv);
    const int tid  = threadIdx.x;
    const int lane = tid & 63;
    const int wav  = tid >> 6;
    for (int e = tid; e < CDIM * CDIM; e += 256)    // e = co*64+ci, coalesced
        Ws[(e & 63) * 65 + (e >> 6)] = ldin(w_proj, e, f);
    __syncthreads();
    int n = blockIdx.x * 4 + wav;          // 432*4 = 1728
    float acc = ldin(b_proj, lane, f);
#pragma unroll 8
    for (int ci = 0; ci < CDIM; ++ci)
        acc = fmaf(O[n * CDIM + ci],                 // uniform -> s_load
                   Ws[ci * 65 + lane], acc);          // bank-conflict-free
    if (f) ((float*)out)[n * CDIM + lane] = acc;
    else   ((__hip_bfloat16*)out)[n * CDIM + lane] = __float2bfloat16(acc);
}

extern "C" void kernel_launch(void* const* d_in, const int* in_sizes, int n_in,
                              void* d_out, int out_size, void* d_ws, size_t ws_size,
                              hipStream_t stream) {
    const void* x      = d_in[0];
    const void* w_qkv  = d_in[1];
    const void* w_proj = d_in[2];
    const void* b_proj = d_in[3];

    // ws layout (~1.11 MB of the proven >=1.77 MB):
    float*        O   = (float*)d_ws;                    // 442368 B [1728][64]
    unsigned int* Qp  = (unsigned int*)(O + N_TOK * CDIM);     // 221184 B
    unsigned int* KVg = Qp + NHEADS * N_TOK;                   // 442368 B

    qkv_pack   <<<dim3(27, 96), 64, 0, stream>>>(x, w_qkv, Qp, KVg);
    attn_kernel<<<dim3(NHT, NHEADS), 256, 0, stream>>>(Qp, (const uint4*)KVg, O);
    proj_kernel<<<432, 256, 0, stream>>>(x, O, w_proj, b_proj, d_out);
}